// Round 7
// baseline (460.568 us; speedup 1.0000x reference)
//
#include <hip/hip_runtime.h>
#include <hip/hip_bf16.h>

// ---------------------------------------------------------------------------
// SelfAttentionLayer fused pipeline for MI355X (gfx950)
// B=4, S=2048, E=1024, H=16, D=64.  ALL tensor inputs/outputs are FP32;
// compute internally in bf16 MFMA + fp32 accum.
// Round 7: attention streams K/V fragments global->VGPR through L1 (fragment
// reads are 16B/lane contiguous; L1 serves the 4x intra-block reuse), LDS
// only holds wave-private Ps -> ZERO barriers in the K-loop. Mask C-init
// from pre-scaled maskS as broadcast float4. GEMMs keep BK=64 (neutral).
// Round-5/6 lessons kept: epilogue lane axis on contiguous output axis.
// ws layout:
//   Wt    : 4 x 1024x1024 bf16 (Wq^T,Wk^T,Wv^T,Wo^T)   8 MB
//   Xb    : (B*S, E) bf16 (x down-converted)           16 MB
//   Qb    : (B,H,S,D) bf16 (pre-scaled by log2e/32)    16 MB
//   Kb    : (B,H,S,D) bf16                             16 MB
//   Vtb   : (B,H,D,S) bf16                             16 MB
//   Ctx   : (B,S,E)  bf16                              16 MB
//   Add   : (B,S,E)  fp32 (proj + bias + residual)     32 MB
//   maskS : (B,S) fp32, mask * (-1e9*log2e)            32 KB
// ---------------------------------------------------------------------------

typedef __bf16 bf16_t;
typedef __bf16 bf16x8 __attribute__((ext_vector_type(8)));
typedef __bf16 bf16x4v __attribute__((ext_vector_type(4)));
typedef float f32x4 __attribute__((ext_vector_type(4)));

#define LDS_AS __attribute__((address_space(3)))
#define GLB_AS __attribute__((address_space(1)))

__device__ __forceinline__ void async16(bf16_t* lds, const bf16_t* g) {
  __builtin_amdgcn_global_load_lds((GLB_AS void*)const_cast<bf16_t*>(g),
                                   (LDS_AS void*)lds, 16, 0, 0);
}

__device__ __forceinline__ f32x4 mfma16(bf16x8 a, bf16x8 b, f32x4 c) {
  return __builtin_amdgcn_mfma_f32_16x16x32_bf16(a, b, c, 0, 0, 0);
}

__device__ __forceinline__ float fast_exp2(float x) {
#if __has_builtin(__builtin_amdgcn_exp2f)
  return __builtin_amdgcn_exp2f(x);
#else
  return __expf(x * 0.6931471805599453f);
#endif
}

// ---------------------------------------------------------------------------
// Kernel 0: x fp32 -> bf16 (blocks 0..8191) + mask prescale (blocks 8192..8199)
// ---------------------------------------------------------------------------
__global__ __launch_bounds__(256) void cvt_x(const float* __restrict__ x,
                                             bf16_t* __restrict__ xb,
                                             const float* __restrict__ mask,
                                             float* __restrict__ maskS)
{
  if (blockIdx.x < 8192) {
    const size_t i = ((size_t)blockIdx.x * 256 + threadIdx.x) * 4;
    const float4 v = *(const float4*)(x + i);
    bf16x4v o;
    o[0] = (bf16_t)v.x; o[1] = (bf16_t)v.y; o[2] = (bf16_t)v.z; o[3] = (bf16_t)v.w;
    *(bf16x4v*)(xb + i) = o;
  } else {
    const size_t i = ((size_t)(blockIdx.x - 8192) * 256 + threadIdx.x) * 4;
    const float4 v = *(const float4*)(mask + i);
    float4 o;
    o.x = v.x * (-1.442695e9f); o.y = v.y * (-1.442695e9f);
    o.z = v.z * (-1.442695e9f); o.w = v.w * (-1.442695e9f);
    *(float4*)(maskS + i) = o;
  }
}

// ---------------------------------------------------------------------------
// Kernel 1: transpose + convert the four 1024x1024 fp32 weights -> bf16 (N,K)
// ---------------------------------------------------------------------------
__global__ __launch_bounds__(256) void transpose_k(
    const float* __restrict__ w0, const float* __restrict__ w1,
    const float* __restrict__ w2, const float* __restrict__ w3,
    bf16_t* __restrict__ dst)
{
  __shared__ bf16_t tile[32][33];
  const float* src = (blockIdx.z == 0) ? w0 : (blockIdx.z == 1) ? w1
                   : (blockIdx.z == 2) ? w2 : w3;
  bf16_t* d = dst + (size_t)blockIdx.z * 1024 * 1024;
  const int bx = blockIdx.x * 32, by = blockIdx.y * 32;
  const int tx = threadIdx.x, ty = threadIdx.y;
#pragma unroll
  for (int r = 0; r < 32; r += 8)
    tile[ty + r][tx] = (bf16_t)src[(size_t)(by + ty + r) * 1024 + bx + tx];
  __syncthreads();
#pragma unroll
  for (int r = 0; r < 32; r += 8)
    d[(size_t)(bx + ty + r) * 1024 + by + tx] = tile[tx][ty + r];
}

// ---------------------------------------------------------------------------
// Kernel 2: QKV GEMM, BK=64.  Round-4 epilogues (lane axis on contiguous dd).
// z=0 -> Q (scaled log2e/32, (B,H,S,D)), z=1 -> K, z=2 -> V^T ((B,H,D,S),
// packed b64 along s).
// ---------------------------------------------------------------------------
__global__ __launch_bounds__(256) void gemm_qkv(
    const bf16_t* __restrict__ X, const bf16_t* __restrict__ WtAll,
    const float* __restrict__ bq, const float* __restrict__ bk,
    const float* __restrict__ bv,
    bf16_t* __restrict__ Qb, bf16_t* __restrict__ Kb, bf16_t* __restrict__ Vtb)
{
  __shared__ __align__(16) bf16_t As[128 * 64];
  __shared__ __align__(16) bf16_t Bs[128 * 64];

  const int z = blockIdx.z;
  const bf16_t* Bt = WtAll + (size_t)z * 1024 * 1024;
  const float* bias = (z == 0) ? bq : (z == 1) ? bk : bv;
  const int bm0 = blockIdx.x * 128;
  const int bn0 = blockIdx.y * 128;
  const int t = threadIdx.x;
  const int w = t >> 6, lane = t & 63;
  const int wm = w >> 1, wn = w & 1;
  const int l15 = lane & 15, quad = lane >> 4;
  const int srow8 = lane >> 3;   // 0..7
  const int sp8   = lane & 7;    // physical granule 0..7

  f32x4 acc[4][4] = {};

  for (int k0 = 0; k0 < 1024; k0 += 64) {
    __syncthreads();
#pragma unroll
    for (int i = 0; i < 4; ++i) {
      const int row = (w * 4 + i) * 8 + srow8;     // 0..127
      const int c = sp8 ^ (row & 7);               // logical k-granule
      async16(&As[row * 64 + sp8 * 8], X  + (size_t)(bm0 + row) * 1024 + k0 + c * 8);
      async16(&Bs[row * 64 + sp8 * 8], Bt + (size_t)(bn0 + row) * 1024 + k0 + c * 8);
    }
    __syncthreads();

    bf16x8 af[4][2], bfr[4][2];
#pragma unroll
    for (int mi = 0; mi < 4; ++mi) {
      const int r = wm * 64 + mi * 16 + l15;
#pragma unroll
      for (int kc = 0; kc < 2; ++kc) {
        const int pg = (kc * 4 + quad) ^ (r & 7);
        af[mi][kc] = *(const bf16x8*)&As[r * 64 + pg * 8];
      }
    }
#pragma unroll
    for (int ni = 0; ni < 4; ++ni) {
      const int r = wn * 64 + ni * 16 + l15;
#pragma unroll
      for (int kc = 0; kc < 2; ++kc) {
        const int pg = (kc * 4 + quad) ^ (r & 7);
        bfr[ni][kc] = *(const bf16x8*)&Bs[r * 64 + pg * 8];
      }
    }
#pragma unroll
    for (int kc = 0; kc < 2; ++kc)
#pragma unroll
      for (int mi = 0; mi < 4; ++mi)
#pragma unroll
        for (int ni = 0; ni < 4; ++ni)
          acc[mi][ni] = mfma16(af[mi][kc], bfr[ni][kc], acc[mi][ni]);
  }

  // log2(e)/32: folds the 1/sqrt(E) score scale and exp->exp2 into Q.
  const float QSCALE = 0.045084220f;

#pragma unroll
  for (int ni = 0; ni < 4; ++ni) {
    const int n = bn0 + wn * 64 + ni * 16 + l15;
    const float bb = bias[n];
    const int h = n >> 6, dd = n & 63;
    if (z == 2) {
      // V^T (B,H,D,S): 4 consecutive s per lane -> packed b64 store
#pragma unroll
      for (int mi = 0; mi < 4; ++mi) {
        const int m0 = bm0 + wm * 64 + mi * 16 + quad * 4;
        const int bi = m0 >> 11, s = m0 & 2047;
        bf16x4v vk;
#pragma unroll
        for (int r = 0; r < 4; ++r) vk[r] = (bf16_t)(acc[mi][ni][r] + bb);
        *(bf16x4v*)&Vtb[((size_t)(bi * 16 + h) * 64 + dd) * 2048 + s] = vk;
      }
    } else {
      // Q/K (B,H,S,D): lane axis (l15 -> dd) is the contiguous axis
#pragma unroll
      for (int mi = 0; mi < 4; ++mi) {
#pragma unroll
        for (int r = 0; r < 4; ++r) {
          const int m = bm0 + wm * 64 + mi * 16 + quad * 4 + r;
          const float v = acc[mi][ni][r] + bb;
          const int bi = m >> 11, s = m & 2047;
          if (z == 0)
            Qb[((size_t)(bi * 16 + h) * 2048 + s) * 64 + dd] = (bf16_t)(v * QSCALE);
          else
            Kb[((size_t)(bi * 16 + h) * 2048 + s) * 64 + dd] = (bf16_t)v;
        }
      }
    }
  }
}

// ---------------------------------------------------------------------------
// Kernel 3: flash attention, S^T formulation, fixed-max exp2 softmax.
// K/V fragments loaded global->VGPR (L1-served 4x reuse); LDS only for
// wave-private Ps; NO barriers in the K-loop.
// ---------------------------------------------------------------------------
__global__ __launch_bounds__(256) void attn_k(
    const bf16_t* __restrict__ Qb, const bf16_t* __restrict__ Kb,
    const bf16_t* __restrict__ Vtb, const float* __restrict__ maskS,
    bf16_t* __restrict__ Ctx)
{
  __shared__ __align__(16) bf16_t Ps[128 * 64];  // [q][s_k], swizzled granules

  const int qt = blockIdx.x, bh = blockIdx.y;
  const int bi = bh >> 4, h = bh & 15;
  const int q0 = qt * 128;
  const bf16_t* Qh = Qb + (size_t)bh * 2048 * 64;
  const bf16_t* Kh = Kb + (size_t)bh * 2048 * 64;
  const bf16_t* Vh = Vtb + (size_t)bh * 64 * 2048;
  const float* mrow = maskS + bi * 2048;

  const int t = threadIdx.x;
  const int w = t >> 6, lane = t & 63;
  const int l15 = lane & 15, quad = lane >> 4;

  // Q as B-fragments: n = q = w*32 + ni*16 + l15, k = kc*32 + quad*8 + j
  bf16x8 qb[2][2];
#pragma unroll
  for (int ni = 0; ni < 2; ++ni)
#pragma unroll
    for (int kc = 0; kc < 2; ++kc)
      qb[ni][kc] = *(const bf16x8*)&Qh[(size_t)(q0 + w * 32 + ni * 16 + l15) * 64
                                       + kc * 32 + quad * 8];

  bf16x8 ones;
#pragma unroll
  for (int i = 0; i < 8; ++i) ones[i] = (bf16_t)1.0f;

  f32x4 oacc[4][2] = {};      // [d-tile][q-tile]
  f32x4 lacc[2] = {};         // row sums via ones-MFMA

  for (int j = 0; j < 32; ++j) {
    const int k0 = j * 64;

    // Direct global->VGPR fragment loads.
    // kf: A-frag of K tile: row s_k = k0+mi*16+l15, k-col = kc*32+quad*8
    // av: A-frag of V^T:   row d   = mi*16+l15,    k-col = k0+kc*32+quad*8
    bf16x8 kf[4][2], av[4][2];
#pragma unroll
    for (int mi = 0; mi < 4; ++mi)
#pragma unroll
      for (int kc = 0; kc < 2; ++kc)
        kf[mi][kc] = *(const bf16x8*)&Kh[(size_t)(k0 + mi * 16 + l15) * 64
                                         + kc * 32 + quad * 8];
#pragma unroll
    for (int mi = 0; mi < 4; ++mi)
#pragma unroll
      for (int kc = 0; kc < 2; ++kc)
        av[mi][kc] = *(const bf16x8*)&Vh[(size_t)(mi * 16 + l15) * 2048
                                         + k0 + kc * 32 + quad * 8];

    // S^T = K . Q^T, C initialized to the (pre-scaled) mask bias
    f32x4 sacc[4][2];
#pragma unroll
    for (int mi = 0; mi < 4; ++mi) {
      const float4 mk = *(const float4*)&mrow[k0 + mi * 16 + quad * 4];
      f32x4 cinit; cinit[0] = mk.x; cinit[1] = mk.y; cinit[2] = mk.z; cinit[3] = mk.w;
#pragma unroll
      for (int ni = 0; ni < 2; ++ni) sacc[mi][ni] = cinit;
    }
#pragma unroll
    for (int mi = 0; mi < 4; ++mi)
#pragma unroll
      for (int ni = 0; ni < 2; ++ni)
#pragma unroll
        for (int kc = 0; kc < 2; ++kc)
          sacc[mi][ni] = mfma16(kf[mi][kc], qb[ni][kc], sacc[mi][ni]);

    // P = exp2(s'), packed b64 LDS writes (rows wave-private, no barrier)
#pragma unroll
    for (int ni = 0; ni < 2; ++ni) {
      const int row = w * 32 + ni * 16 + l15;
#pragma unroll
      for (int mi = 0; mi < 4; ++mi) {
        bf16x4v pk;
        pk[0] = (bf16_t)fast_exp2(sacc[mi][ni][0]);
        pk[1] = (bf16_t)fast_exp2(sacc[mi][ni][1]);
        pk[2] = (bf16_t)fast_exp2(sacc[mi][ni][2]);
        pk[3] = (bf16_t)fast_exp2(sacc[mi][ni][3]);
        const int pg = (mi * 2 + (quad >> 1)) ^ (row & 7);
        *(bf16x4v*)&Ps[row * 64 + pg * 8 + (quad & 1) * 4] = pk;
      }
    }

    // O^T += V^T . P ; l += ones . P   (same-wave LDS ordering via lgkmcnt)
    bf16x8 pb[2][2];
#pragma unroll
    for (int ni = 0; ni < 2; ++ni)
#pragma unroll
      for (int kc = 0; kc < 2; ++kc) {
        const int row = w * 32 + ni * 16 + l15;
        const int pg = (kc * 4 + quad) ^ (row & 7);
        pb[ni][kc] = *(const bf16x8*)&Ps[row * 64 + pg * 8];
      }
#pragma unroll
    for (int mi = 0; mi < 4; ++mi)
#pragma unroll
      for (int ni = 0; ni < 2; ++ni)
#pragma unroll
        for (int kc = 0; kc < 2; ++kc)
          oacc[mi][ni] = mfma16(av[mi][kc], pb[ni][kc], oacc[mi][ni]);
#pragma unroll
    for (int ni = 0; ni < 2; ++ni)
#pragma unroll
      for (int kc = 0; kc < 2; ++kc)
        lacc[ni] = mfma16(ones, pb[ni][kc], lacc[ni]);
  }

  // write ctx (B,S,E): lane holds O[q = ni*16+l15][d = mi*16+quad*4+r]
#pragma unroll
  for (int ni = 0; ni < 2; ++ni) {
    const float inv = 1.0f / lacc[ni][0];
    const int s = q0 + w * 32 + ni * 16 + l15;
#pragma unroll
    for (int mi = 0; mi < 4; ++mi) {
      bf16x4v o4;
      o4[0] = (bf16_t)(oacc[mi][ni][0] * inv);
      o4[1] = (bf16_t)(oacc[mi][ni][1] * inv);
      o4[2] = (bf16_t)(oacc[mi][ni][2] * inv);
      o4[3] = (bf16_t)(oacc[mi][ni][3] * inv);
      *(bf16x4v*)&Ctx[((size_t)bi * 2048 + s) * 1024 + h * 64 + mi * 16 + quad * 4] = o4;
    }
  }
}

// ---------------------------------------------------------------------------
// Kernel 4: output projection + bias + residual -> fp32 Add.  BK=64,
// round-4 epilogue (lane axis on contiguous n).
// ---------------------------------------------------------------------------
__global__ __launch_bounds__(256) void gemm_proj(
    const bf16_t* __restrict__ Ctx, const bf16_t* __restrict__ WoT,
    const float* __restrict__ bo, const float* __restrict__ Xres,
    float* __restrict__ Add)
{
  __shared__ __align__(16) bf16_t As[128 * 64];
  __shared__ __align__(16) bf16_t Bs[128 * 64];

  const int bm0 = blockIdx.x * 128;
  const int bn0 = blockIdx.y * 128;
  const int t = threadIdx.x;
  const int w = t >> 6, lane = t & 63;
  const int wm = w >> 1, wn = w & 1;
  const int l15 = lane & 15, quad = lane >> 4;
  const int srow8 = lane >> 3;
  const int sp8   = lane & 7;

  f32x4 acc[4][4] = {};

  for (int k0 = 0; k0 < 1024; k0 += 64) {
    __syncthreads();
#pragma unroll
    for (int i = 0; i < 4; ++i) {
      const int row = (w * 4 + i) * 8 + srow8;
      const int c = sp8 ^ (row & 7);
      async16(&As[row * 64 + sp8 * 8], Ctx + (size_t)(bm0 + row) * 1024 + k0 + c * 8);
      async16(&Bs[row * 64 + sp8 * 8], WoT + (size_t)(bn0 + row) * 1024 + k0 + c * 8);
    }
    __syncthreads();

    bf16x8 af[4][2], bfr[4][2];
#pragma unroll
    for (int mi = 0; mi < 4; ++mi) {
      const int r = wm * 64 + mi * 16 + l15;
#pragma unroll
      for (int kc = 0; kc < 2; ++kc) {
        const int pg = (kc * 4 + quad) ^ (r & 7);
        af[mi][kc] = *(const bf16x8*)&As[r * 64 + pg * 8];
      }
    }
#pragma unroll
    for (int ni = 0; ni < 4; ++ni) {
      const int r = wn * 64 + ni * 16 + l15;
#pragma unroll
      for (int kc = 0; kc < 2; ++kc) {
        const int pg = (kc * 4 + quad) ^ (r & 7);
        bfr[ni][kc] = *(const bf16x8*)&Bs[r * 64 + pg * 8];
      }
    }
#pragma unroll
    for (int kc = 0; kc < 2; ++kc)
#pragma unroll
      for (int mi = 0; mi < 4; ++mi)
#pragma unroll
        for (int ni = 0; ni < 4; ++ni)
          acc[mi][ni] = mfma16(af[mi][kc], bfr[ni][kc], acc[mi][ni]);
  }

#pragma unroll
  for (int ni = 0; ni < 4; ++ni) {
    const int n = bn0 + wn * 64 + ni * 16 + l15;
    const float bb = bo[n];
#pragma unroll
    for (int mi = 0; mi < 4; ++mi) {
#pragma unroll
      for (int r = 0; r < 4; ++r) {
        const int m = bm0 + wm * 64 + mi * 16 + quad * 4 + r;
        Add[(size_t)m * 1024 + n] =
            acc[mi][ni][r] + bb + Xres[(size_t)m * 1024 + n];
      }
    }
  }
}

// ---------------------------------------------------------------------------
// Kernel 5: LayerNorm over E=1024, one block per row, fp32 in/out
// ---------------------------------------------------------------------------
__global__ __launch_bounds__(256) void ln_k(
    const float* __restrict__ A, const float* __restrict__ gamma,
    const float* __restrict__ beta, float* __restrict__ out)
{
  __shared__ float red[8];
  const int row = blockIdx.x, t = threadIdx.x;
  const float4 v = ((const float4*)(A + (size_t)row * 1024))[t];
  float s = v.x + v.y + v.z + v.w;
#pragma unroll
  for (int o = 32; o >= 1; o >>= 1) s += __shfl_xor(s, o);
  if ((t & 63) == 0) red[t >> 6] = s;
  __syncthreads();
  const float mu = (red[0] + red[1] + red[2] + red[3]) * (1.0f / 1024.0f);
  const float dx = v.x - mu, dy = v.y - mu, dz = v.z - mu, dw = v.w - mu;
  float q = dx * dx + dy * dy + dz * dz + dw * dw;
#pragma unroll
  for (int o = 32; o >= 1; o >>= 1) q += __shfl_xor(q, o);
  if ((t & 63) == 0) red[4 + (t >> 6)] = q;
  __syncthreads();
  const float var = (red[4] + red[5] + red[6] + red[7]) * (1.0f / 1024.0f);
  const float rs = rsqrtf(var + 1e-6f);

  const int c0 = t * 4;
  float4 o4;
  o4.x = gamma[c0 + 0] * dx * rs + beta[c0 + 0];
  o4.y = gamma[c0 + 1] * dy * rs + beta[c0 + 1];
  o4.z = gamma[c0 + 2] * dz * rs + beta[c0 + 2];
  o4.w = gamma[c0 + 3] * dw * rs + beta[c0 + 3];
  *(float4*)(out + (size_t)row * 1024 + c0) = o4;
}

// ---------------------------------------------------------------------------
extern "C" void kernel_launch(void* const* d_in, const int* in_sizes, int n_in,
                              void* d_out, int out_size, void* d_ws, size_t ws_size,
                              hipStream_t stream)
{
  const float* x     = (const float*)d_in[0];
  const float* mask  = (const float*)d_in[1];
  const float* Wq    = (const float*)d_in[2];
  const float* bq    = (const float*)d_in[3];
  const float* Wk    = (const float*)d_in[4];
  const float* bk    = (const float*)d_in[5];
  const float* Wv    = (const float*)d_in[6];
  const float* bv    = (const float*)d_in[7];
  const float* Wo    = (const float*)d_in[8];
  const float* bo    = (const float*)d_in[9];
  const float* gamma = (const float*)d_in[10];
  const float* beta  = (const float*)d_in[11];
  float* out = (float*)d_out;

  bf16_t* Wt    = (bf16_t*)d_ws;
  bf16_t* Xb    = Wt + (size_t)4 * 1024 * 1024;
  bf16_t* Qb    = Xb + (size_t)8192 * 1024;
  bf16_t* Kb    = Qb + (size_t)8192 * 1024;
  bf16_t* Vtb   = Kb + (size_t)8192 * 1024;
  bf16_t* Ctx   = Vtb + (size_t)8192 * 1024;
  float*  Add   = (float*)(Ctx + (size_t)8192 * 1024);
  float*  maskS = Add + (size_t)8192 * 1024;

  cvt_x<<<8200, 256, 0, stream>>>(x, Xb, mask, maskS);
  transpose_k<<<dim3(32, 32, 4), dim3(32, 8), 0, stream>>>(Wq, Wk, Wv, Wo, Wt);
  gemm_qkv<<<dim3(64, 8, 3), 256, 0, stream>>>(Xb, Wt, bq, bk, bv, Qb, Kb, Vtb);
  attn_k<<<dim3(16, 64), 256, 0, stream>>>(Qb, Kb, Vtb, maskS, Ctx);
  gemm_proj<<<dim3(64, 8), 256, 0, stream>>>(Ctx, Wt + (size_t)3 * 1024 * 1024, bo, x, Add);
  ln_k<<<8192, 256, 0, stream>>>(Add, gamma, beta, out);
}

// Round 8
// 307.965 us; speedup vs baseline: 1.4955x; 1.4955x over previous
//
#include <hip/hip_runtime.h>
#include <hip/hip_bf16.h>

// ---------------------------------------------------------------------------
// SelfAttentionLayer fused pipeline for MI355X (gfx950)
// B=4, S=2048, E=1024, H=16, D=64.  ALL tensor inputs/outputs are FP32;
// compute internally in bf16 MFMA + fp32 accum.
// Round 8: RECOVERY to measured-best composite.
//   - attn: round-4 kernel verbatim (103.4 us measured): LDS-staged K/V
//     (global_load_lds is the latency-hiding engine — round 7 proved removing
//     it makes the kernel latency-bound), fixed-max exp2 softmax, ones-MFMA
//     row sums, wave-private Ps (no third barrier).
//   - GEMMs: BK=64 (round-6 measured slight winner vs BK=32).
//   - Epilogue lane axis stays on the contiguous output axis (round-5 lesson).
// ws layout:
//   Wt   : 4 x 1024x1024 bf16 (Wq^T,Wk^T,Wv^T,Wo^T)   8 MB
//   Xb   : (B*S, E) bf16 (x down-converted)           16 MB
//   Qb   : (B,H,S,D) bf16 (pre-scaled by log2e/32)    16 MB
//   Kb   : (B,H,S,D) bf16                             16 MB
//   Vtb  : (B,H,D,S) bf16                             16 MB
//   Ctx  : (B,S,E)  bf16                              16 MB
//   Add  : (B,S,E)  fp32 (proj + bias + residual)     32 MB
// ---------------------------------------------------------------------------

typedef __bf16 bf16_t;
typedef __bf16 bf16x8 __attribute__((ext_vector_type(8)));
typedef __bf16 bf16x4v __attribute__((ext_vector_type(4)));
typedef float f32x4 __attribute__((ext_vector_type(4)));

#define LDS_AS __attribute__((address_space(3)))
#define GLB_AS __attribute__((address_space(1)))

__device__ __forceinline__ void async16(bf16_t* lds, const bf16_t* g) {
  __builtin_amdgcn_global_load_lds((GLB_AS void*)const_cast<bf16_t*>(g),
                                   (LDS_AS void*)lds, 16, 0, 0);
}

__device__ __forceinline__ f32x4 mfma16(bf16x8 a, bf16x8 b, f32x4 c) {
  return __builtin_amdgcn_mfma_f32_16x16x32_bf16(a, b, c, 0, 0, 0);
}

__device__ __forceinline__ float fast_exp2(float x) {
#if __has_builtin(__builtin_amdgcn_exp2f)
  return __builtin_amdgcn_exp2f(x);
#else
  return __expf(x * 0.6931471805599453f);
#endif
}

// ---------------------------------------------------------------------------
// Kernel 0: x fp32 -> bf16
// ---------------------------------------------------------------------------
__global__ __launch_bounds__(256) void cvt_x(const float* __restrict__ x,
                                             bf16_t* __restrict__ xb)
{
  const size_t i = ((size_t)blockIdx.x * 256 + threadIdx.x) * 4;
  const float4 v = *(const float4*)(x + i);
  bf16x4v o;
  o[0] = (bf16_t)v.x; o[1] = (bf16_t)v.y; o[2] = (bf16_t)v.z; o[3] = (bf16_t)v.w;
  *(bf16x4v*)(xb + i) = o;
}

// ---------------------------------------------------------------------------
// Kernel 1: transpose + convert the four 1024x1024 fp32 weights -> bf16 (N,K)
// ---------------------------------------------------------------------------
__global__ __launch_bounds__(256) void transpose_k(
    const float* __restrict__ w0, const float* __restrict__ w1,
    const float* __restrict__ w2, const float* __restrict__ w3,
    bf16_t* __restrict__ dst)
{
  __shared__ bf16_t tile[32][33];
  const float* src = (blockIdx.z == 0) ? w0 : (blockIdx.z == 1) ? w1
                   : (blockIdx.z == 2) ? w2 : w3;
  bf16_t* d = dst + (size_t)blockIdx.z * 1024 * 1024;
  const int bx = blockIdx.x * 32, by = blockIdx.y * 32;
  const int tx = threadIdx.x, ty = threadIdx.y;
#pragma unroll
  for (int r = 0; r < 32; r += 8)
    tile[ty + r][tx] = (bf16_t)src[(size_t)(by + ty + r) * 1024 + bx + tx];
  __syncthreads();
#pragma unroll
  for (int r = 0; r < 32; r += 8)
    d[(size_t)(bx + ty + r) * 1024 + by + tx] = tile[tx][ty + r];
}

// ---------------------------------------------------------------------------
// Kernel 2: QKV GEMM, BK=64.  Round-4 epilogues (lane axis on contiguous dd).
// z=0 -> Q (scaled log2e/32, (B,H,S,D)), z=1 -> K, z=2 -> V^T ((B,H,D,S),
// packed b64 along s).
// ---------------------------------------------------------------------------
__global__ __launch_bounds__(256) void gemm_qkv(
    const bf16_t* __restrict__ X, const bf16_t* __restrict__ WtAll,
    const float* __restrict__ bq, const float* __restrict__ bk,
    const float* __restrict__ bv,
    bf16_t* __restrict__ Qb, bf16_t* __restrict__ Kb, bf16_t* __restrict__ Vtb)
{
  __shared__ __align__(16) bf16_t As[128 * 64];
  __shared__ __align__(16) bf16_t Bs[128 * 64];

  const int z = blockIdx.z;
  const bf16_t* Bt = WtAll + (size_t)z * 1024 * 1024;
  const float* bias = (z == 0) ? bq : (z == 1) ? bk : bv;
  const int bm0 = blockIdx.x * 128;
  const int bn0 = blockIdx.y * 128;
  const int t = threadIdx.x;
  const int w = t >> 6, lane = t & 63;
  const int wm = w >> 1, wn = w & 1;
  const int l15 = lane & 15, quad = lane >> 4;
  const int srow8 = lane >> 3;   // 0..7
  const int sp8   = lane & 7;    // physical granule 0..7

  f32x4 acc[4][4] = {};

  for (int k0 = 0; k0 < 1024; k0 += 64) {
    __syncthreads();
#pragma unroll
    for (int i = 0; i < 4; ++i) {
      const int row = (w * 4 + i) * 8 + srow8;     // 0..127
      const int c = sp8 ^ (row & 7);               // logical k-granule
      async16(&As[row * 64 + sp8 * 8], X  + (size_t)(bm0 + row) * 1024 + k0 + c * 8);
      async16(&Bs[row * 64 + sp8 * 8], Bt + (size_t)(bn0 + row) * 1024 + k0 + c * 8);
    }
    __syncthreads();

    bf16x8 af[4][2], bfr[4][2];
#pragma unroll
    for (int mi = 0; mi < 4; ++mi) {
      const int r = wm * 64 + mi * 16 + l15;
#pragma unroll
      for (int kc = 0; kc < 2; ++kc) {
        const int pg = (kc * 4 + quad) ^ (r & 7);
        af[mi][kc] = *(const bf16x8*)&As[r * 64 + pg * 8];
      }
    }
#pragma unroll
    for (int ni = 0; ni < 4; ++ni) {
      const int r = wn * 64 + ni * 16 + l15;
#pragma unroll
      for (int kc = 0; kc < 2; ++kc) {
        const int pg = (kc * 4 + quad) ^ (r & 7);
        bfr[ni][kc] = *(const bf16x8*)&Bs[r * 64 + pg * 8];
      }
    }
#pragma unroll
    for (int kc = 0; kc < 2; ++kc)
#pragma unroll
      for (int mi = 0; mi < 4; ++mi)
#pragma unroll
        for (int ni = 0; ni < 4; ++ni)
          acc[mi][ni] = mfma16(af[mi][kc], bfr[ni][kc], acc[mi][ni]);
  }

  // log2(e)/32: folds the 1/sqrt(E) score scale and exp->exp2 into Q.
  const float QSCALE = 0.045084220f;

#pragma unroll
  for (int ni = 0; ni < 4; ++ni) {
    const int n = bn0 + wn * 64 + ni * 16 + l15;
    const float bb = bias[n];
    const int h = n >> 6, dd = n & 63;
    if (z == 2) {
      // V^T (B,H,D,S): 4 consecutive s per lane -> packed b64 store
#pragma unroll
      for (int mi = 0; mi < 4; ++mi) {
        const int m0 = bm0 + wm * 64 + mi * 16 + quad * 4;
        const int bi = m0 >> 11, s = m0 & 2047;
        bf16x4v vk;
#pragma unroll
        for (int r = 0; r < 4; ++r) vk[r] = (bf16_t)(acc[mi][ni][r] + bb);
        *(bf16x4v*)&Vtb[((size_t)(bi * 16 + h) * 64 + dd) * 2048 + s] = vk;
      }
    } else {
      // Q/K (B,H,S,D): lane axis (l15 -> dd) is the contiguous axis
#pragma unroll
      for (int mi = 0; mi < 4; ++mi) {
#pragma unroll
        for (int r = 0; r < 4; ++r) {
          const int m = bm0 + wm * 64 + mi * 16 + quad * 4 + r;
          const float v = acc[mi][ni][r] + bb;
          const int bi = m >> 11, s = m & 2047;
          if (z == 0)
            Qb[((size_t)(bi * 16 + h) * 2048 + s) * 64 + dd] = (bf16_t)(v * QSCALE);
          else
            Kb[((size_t)(bi * 16 + h) * 2048 + s) * 64 + dd] = (bf16_t)v;
        }
      }
    }
  }
}

// ---------------------------------------------------------------------------
// Kernel 3: flash attention, S^T formulation, fixed-max exp2 softmax.
// ROUND-4 VERBATIM (measured 103.4 us): LDS-staged K/V via global_load_lds,
// in-kernel maskv staging, wave-private Ps, 2 barriers/iter.
// ---------------------------------------------------------------------------
__global__ __launch_bounds__(256) void attn_k(
    const bf16_t* __restrict__ Qb, const bf16_t* __restrict__ Kb,
    const bf16_t* __restrict__ Vtb, const float* __restrict__ mask,
    bf16_t* __restrict__ Ctx)
{
  __shared__ __align__(16) bf16_t Ks[64 * 64];   // [s_k][d], swizzled granules
  __shared__ __align__(16) bf16_t Vs[64 * 64];   // [d][s_k], swizzled granules
  __shared__ __align__(16) bf16_t Ps[128 * 64];  // [q][s_k], swizzled granules
  __shared__ __align__(16) float maskv[64];

  const int qt = blockIdx.x, bh = blockIdx.y;
  const int bi = bh >> 4, h = bh & 15;
  const int q0 = qt * 128;
  const bf16_t* Qh = Qb + (size_t)bh * 2048 * 64;
  const bf16_t* Kh = Kb + (size_t)bh * 2048 * 64;
  const bf16_t* Vh = Vtb + (size_t)bh * 64 * 2048;

  const int t = threadIdx.x;
  const int w = t >> 6, lane = t & 63;
  const int l15 = lane & 15, quad = lane >> 4;

  bf16x8 qb[2][2];
#pragma unroll
  for (int ni = 0; ni < 2; ++ni)
#pragma unroll
    for (int kc = 0; kc < 2; ++kc)
      qb[ni][kc] = *(const bf16x8*)&Qh[(size_t)(q0 + w * 32 + ni * 16 + l15) * 64
                                       + kc * 32 + quad * 8];

  bf16x8 ones;
#pragma unroll
  for (int i = 0; i < 8; ++i) ones[i] = (bf16_t)1.0f;

  f32x4 oacc[4][2] = {};      // [d-tile][q-tile]
  f32x4 lacc[2] = {};         // row sums via ones-MFMA

  const int srow = lane >> 3;
  const int sp = lane & 7;

  for (int j = 0; j < 32; ++j) {
    const int k0 = j * 64;
    __syncthreads();
#pragma unroll
    for (int i = 0; i < 2; ++i) {
      const int row = (w * 2 + i) * 8 + srow;
      const int c = sp ^ (row & 7);
      async16(&Ks[row * 64 + sp * 8], Kh + (size_t)(k0 + row) * 64 + c * 8);
      async16(&Vs[row * 64 + sp * 8], Vh + (size_t)row * 2048 + k0 + c * 8);
    }
    // mask bias pre-scaled by log2(e) (exp2 domain)
    if (t < 64) maskv[t] = mask[bi * 2048 + k0 + t] * (-1.442695e9f);
    __syncthreads();

    // S^T = K . Q^T, C initialized to the mask bias (free mask add)
    f32x4 sacc[4][2];
#pragma unroll
    for (int mi = 0; mi < 4; ++mi) {
      const float4 mk = *(const float4*)&maskv[mi * 16 + quad * 4];
      f32x4 cinit; cinit[0] = mk.x; cinit[1] = mk.y; cinit[2] = mk.z; cinit[3] = mk.w;
#pragma unroll
      for (int ni = 0; ni < 2; ++ni) sacc[mi][ni] = cinit;
    }
    bf16x8 kf[4][2];
#pragma unroll
    for (int mi = 0; mi < 4; ++mi)
#pragma unroll
      for (int kc = 0; kc < 2; ++kc) {
        const int r = mi * 16 + l15;
        const int pg = (kc * 4 + quad) ^ (r & 7);
        kf[mi][kc] = *(const bf16x8*)&Ks[r * 64 + pg * 8];
      }
#pragma unroll
    for (int mi = 0; mi < 4; ++mi)
#pragma unroll
      for (int ni = 0; ni < 2; ++ni)
#pragma unroll
        for (int kc = 0; kc < 2; ++kc)
          sacc[mi][ni] = mfma16(kf[mi][kc], qb[ni][kc], sacc[mi][ni]);

    // P = exp2(s'): no max tracking (scores bounded), packed b64 LDS writes
#pragma unroll
    for (int ni = 0; ni < 2; ++ni) {
      const int row = w * 32 + ni * 16 + l15;
#pragma unroll
      for (int mi = 0; mi < 4; ++mi) {
        bf16x4v pk;
        pk[0] = (bf16_t)fast_exp2(sacc[mi][ni][0]);
        pk[1] = (bf16_t)fast_exp2(sacc[mi][ni][1]);
        pk[2] = (bf16_t)fast_exp2(sacc[mi][ni][2]);
        pk[3] = (bf16_t)fast_exp2(sacc[mi][ni][3]);
        const int pg = (mi * 2 + (quad >> 1)) ^ (row & 7);
        *(bf16x4v*)&Ps[row * 64 + pg * 8 + (quad & 1) * 4] = pk;
      }
    }

    // O^T += V^T . P ; l += ones . P   (Ps rows wave-private: no barrier)
    bf16x8 av[4][2], pb[2][2];
#pragma unroll
    for (int ni = 0; ni < 2; ++ni)
#pragma unroll
      for (int kc = 0; kc < 2; ++kc) {
        const int row = w * 32 + ni * 16 + l15;
        const int pg = (kc * 4 + quad) ^ (row & 7);
        pb[ni][kc] = *(const bf16x8*)&Ps[row * 64 + pg * 8];
      }
#pragma unroll
    for (int mi = 0; mi < 4; ++mi)
#pragma unroll
      for (int kc = 0; kc < 2; ++kc) {
        const int r = mi * 16 + l15;
        const int pg = (kc * 4 + quad) ^ (r & 7);
        av[mi][kc] = *(const bf16x8*)&Vs[r * 64 + pg * 8];
      }
#pragma unroll
    for (int mi = 0; mi < 4; ++mi)
#pragma unroll
      for (int ni = 0; ni < 2; ++ni)
#pragma unroll
        for (int kc = 0; kc < 2; ++kc)
          oacc[mi][ni] = mfma16(av[mi][kc], pb[ni][kc], oacc[mi][ni]);
#pragma unroll
    for (int ni = 0; ni < 2; ++ni)
#pragma unroll
      for (int kc = 0; kc < 2; ++kc)
        lacc[ni] = mfma16(ones, pb[ni][kc], lacc[ni]);
  }

  // write ctx (B,S,E): lane holds O[q = ni*16+l15][d = mi*16+quad*4+r]
#pragma unroll
  for (int ni = 0; ni < 2; ++ni) {
    const float inv = 1.0f / lacc[ni][0];
    const int s = q0 + w * 32 + ni * 16 + l15;
#pragma unroll
    for (int mi = 0; mi < 4; ++mi) {
      bf16x4v o4;
      o4[0] = (bf16_t)(oacc[mi][ni][0] * inv);
      o4[1] = (bf16_t)(oacc[mi][ni][1] * inv);
      o4[2] = (bf16_t)(oacc[mi][ni][2] * inv);
      o4[3] = (bf16_t)(oacc[mi][ni][3] * inv);
      *(bf16x4v*)&Ctx[((size_t)bi * 2048 + s) * 1024 + h * 64 + mi * 16 + quad * 4] = o4;
    }
  }
}

// ---------------------------------------------------------------------------
// Kernel 4: output projection + bias + residual -> fp32 Add.  BK=64,
// round-4 epilogue (lane axis on contiguous n).
// ---------------------------------------------------------------------------
__global__ __launch_bounds__(256) void gemm_proj(
    const bf16_t* __restrict__ Ctx, const bf16_t* __restrict__ WoT,
    const float* __restrict__ bo, const float* __restrict__ Xres,
    float* __restrict__ Add)
{
  __shared__ __align__(16) bf16_t As[128 * 64];
  __shared__ __align__(16) bf16_t Bs[128 * 64];

  const int bm0 = blockIdx.x * 128;
  const int bn0 = blockIdx.y * 128;
  const int t = threadIdx.x;
  const int w = t >> 6, lane = t & 63;
  const int wm = w >> 1, wn = w & 1;
  const int l15 = lane & 15, quad = lane >> 4;
  const int srow8 = lane >> 3;
  const int sp8   = lane & 7;

  f32x4 acc[4][4] = {};

  for (int k0 = 0; k0 < 1024; k0 += 64) {
    __syncthreads();
#pragma unroll
    for (int i = 0; i < 4; ++i) {
      const int row = (w * 4 + i) * 8 + srow8;
      const int c = sp8 ^ (row & 7);
      async16(&As[row * 64 + sp8 * 8], Ctx + (size_t)(bm0 + row) * 1024 + k0 + c * 8);
      async16(&Bs[row * 64 + sp8 * 8], WoT + (size_t)(bn0 + row) * 1024 + k0 + c * 8);
    }
    __syncthreads();

    bf16x8 af[4][2], bfr[4][2];
#pragma unroll
    for (int mi = 0; mi < 4; ++mi) {
      const int r = wm * 64 + mi * 16 + l15;
#pragma unroll
      for (int kc = 0; kc < 2; ++kc) {
        const int pg = (kc * 4 + quad) ^ (r & 7);
        af[mi][kc] = *(const bf16x8*)&As[r * 64 + pg * 8];
      }
    }
#pragma unroll
    for (int ni = 0; ni < 4; ++ni) {
      const int r = wn * 64 + ni * 16 + l15;
#pragma unroll
      for (int kc = 0; kc < 2; ++kc) {
        const int pg = (kc * 4 + quad) ^ (r & 7);
        bfr[ni][kc] = *(const bf16x8*)&Bs[r * 64 + pg * 8];
      }
    }
#pragma unroll
    for (int kc = 0; kc < 2; ++kc)
#pragma unroll
      for (int mi = 0; mi < 4; ++mi)
#pragma unroll
        for (int ni = 0; ni < 4; ++ni)
          acc[mi][ni] = mfma16(af[mi][kc], bfr[ni][kc], acc[mi][ni]);
  }

#pragma unroll
  for (int ni = 0; ni < 4; ++ni) {
    const int n = bn0 + wn * 64 + ni * 16 + l15;
    const float bb = bo[n];
#pragma unroll
    for (int mi = 0; mi < 4; ++mi) {
#pragma unroll
      for (int r = 0; r < 4; ++r) {
        const int m = bm0 + wm * 64 + mi * 16 + quad * 4 + r;
        Add[(size_t)m * 1024 + n] =
            acc[mi][ni][r] + bb + Xres[(size_t)m * 1024 + n];
      }
    }
  }
}

// ---------------------------------------------------------------------------
// Kernel 5: LayerNorm over E=1024, one block per row, fp32 in/out
// ---------------------------------------------------------------------------
__global__ __launch_bounds__(256) void ln_k(
    const float* __restrict__ A, const float* __restrict__ gamma,
    const float* __restrict__ beta, float* __restrict__ out)
{
  __shared__ float red[8];
  const int row = blockIdx.x, t = threadIdx.x;
  const float4 v = ((const float4*)(A + (size_t)row * 1024))[t];
  float s = v.x + v.y + v.z + v.w;
#pragma unroll
  for (int o = 32; o >= 1; o >>= 1) s += __shfl_xor(s, o);
  if ((t & 63) == 0) red[t >> 6] = s;
  __syncthreads();
  const float mu = (red[0] + red[1] + red[2] + red[3]) * (1.0f / 1024.0f);
  const float dx = v.x - mu, dy = v.y - mu, dz = v.z - mu, dw = v.w - mu;
  float q = dx * dx + dy * dy + dz * dz + dw * dw;
#pragma unroll
  for (int o = 32; o >= 1; o >>= 1) q += __shfl_xor(q, o);
  if ((t & 63) == 0) red[4 + (t >> 6)] = q;
  __syncthreads();
  const float var = (red[4] + red[5] + red[6] + red[7]) * (1.0f / 1024.0f);
  const float rs = rsqrtf(var + 1e-6f);

  const int c0 = t * 4;
  float4 o4;
  o4.x = gamma[c0 + 0] * dx * rs + beta[c0 + 0];
  o4.y = gamma[c0 + 1] * dy * rs + beta[c0 + 1];
  o4.z = gamma[c0 + 2] * dz * rs + beta[c0 + 2];
  o4.w = gamma[c0 + 3] * dw * rs + beta[c0 + 3];
  *(float4*)(out + (size_t)row * 1024 + c0) = o4;
}

// ---------------------------------------------------------------------------
extern "C" void kernel_launch(void* const* d_in, const int* in_sizes, int n_in,
                              void* d_out, int out_size, void* d_ws, size_t ws_size,
                              hipStream_t stream)
{
  const float* x     = (const float*)d_in[0];
  const float* mask  = (const float*)d_in[1];
  const float* Wq    = (const float*)d_in[2];
  const float* bq    = (const float*)d_in[3];
  const float* Wk    = (const float*)d_in[4];
  const float* bk    = (const float*)d_in[5];
  const float* Wv    = (const float*)d_in[6];
  const float* bv    = (const float*)d_in[7];
  const float* Wo    = (const float*)d_in[8];
  const float* bo    = (const float*)d_in[9];
  const float* gamma = (const float*)d_in[10];
  const float* beta  = (const float*)d_in[11];
  float* out = (float*)d_out;

  bf16_t* Wt  = (bf16_t*)d_ws;
  bf16_t* Xb  = Wt + (size_t)4 * 1024 * 1024;
  bf16_t* Qb  = Xb + (size_t)8192 * 1024;
  bf16_t* Kb  = Qb + (size_t)8192 * 1024;
  bf16_t* Vtb = Kb + (size_t)8192 * 1024;
  bf16_t* Ctx = Vtb + (size_t)8192 * 1024;
  float*  Add = (float*)(Ctx + (size_t)8192 * 1024);

  cvt_x<<<8192, 256, 0, stream>>>(x, Xb);
  transpose_k<<<dim3(32, 32, 4), dim3(32, 8), 0, stream>>>(Wq, Wk, Wv, Wo, Wt);
  gemm_qkv<<<dim3(64, 8, 3), 256, 0, stream>>>(Xb, Wt, bq, bk, bv, Qb, Kb, Vtb);
  attn_k<<<dim3(16, 64), 256, 0, stream>>>(Qb, Kb, Vtb, mask, Ctx);
  gemm_proj<<<dim3(64, 8), 256, 0, stream>>>(Ctx, Wt + (size_t)3 * 1024 * 1024, bo, x, Add);
  ln_k<<<8192, 256, 0, stream>>>(Add, gamma, beta, out);
}

// Round 9
// 300.376 us; speedup vs baseline: 1.5333x; 1.0253x over previous
//
#include <hip/hip_runtime.h>
#include <hip/hip_bf16.h>

// ---------------------------------------------------------------------------
// SelfAttentionLayer fused pipeline for MI355X (gfx950)
// B=4, S=2048, E=1024, H=16, D=64.  ALL tensor inputs/outputs are FP32;
// compute internally in bf16 MFMA + fp32 accum.
// Round 9:
//   - attn: Q-tile 256, 64 q per wave (was 32). The LDS datapath was the
//     binding resource (~66 us busy: 4 waves re-read identical K/V frags).
//     Doubling q/wave cuts LDS instructions per unit work by 29%.
//     kf/av loads serialized per-mi to cap VGPR. Occupancy 2 blocks/CU
//     (grid 512 = exactly 2/CU), LDS staging retained (latency engine).
//   - ln_k: wave-per-row, no LDS, no barriers (4 rows / 256-thr block).
//   - cvt_x fused into transpose launch (z=4).
//   - GEMMs unchanged (BK=64, round-8 form).
// ws layout:
//   Wt   : 4 x 1024x1024 bf16 (Wq^T,Wk^T,Wv^T,Wo^T)   8 MB
//   Xb   : (B*S, E) bf16 (x down-converted)           16 MB
//   Qb   : (B,H,S,D) bf16 (pre-scaled by log2e/32)    16 MB
//   Kb   : (B,H,S,D) bf16                             16 MB
//   Vtb  : (B,H,D,S) bf16                             16 MB
//   Ctx  : (B,S,E)  bf16                              16 MB
//   Add  : (B,S,E)  fp32 (proj + bias + residual)     32 MB
// ---------------------------------------------------------------------------

typedef __bf16 bf16_t;
typedef __bf16 bf16x8 __attribute__((ext_vector_type(8)));
typedef __bf16 bf16x4v __attribute__((ext_vector_type(4)));
typedef float f32x4 __attribute__((ext_vector_type(4)));

#define LDS_AS __attribute__((address_space(3)))
#define GLB_AS __attribute__((address_space(1)))

__device__ __forceinline__ void async16(bf16_t* lds, const bf16_t* g) {
  __builtin_amdgcn_global_load_lds((GLB_AS void*)const_cast<bf16_t*>(g),
                                   (LDS_AS void*)lds, 16, 0, 0);
}

__device__ __forceinline__ f32x4 mfma16(bf16x8 a, bf16x8 b, f32x4 c) {
  return __builtin_amdgcn_mfma_f32_16x16x32_bf16(a, b, c, 0, 0, 0);
}

__device__ __forceinline__ float fast_exp2(float x) {
#if __has_builtin(__builtin_amdgcn_exp2f)
  return __builtin_amdgcn_exp2f(x);
#else
  return __expf(x * 0.6931471805599453f);
#endif
}

// ---------------------------------------------------------------------------
// Kernel 1: weight transpose+cvt (z=0..3) and x fp32->bf16 (z=4)
// ---------------------------------------------------------------------------
__global__ __launch_bounds__(256) void prep_k(
    const float* __restrict__ w0, const float* __restrict__ w1,
    const float* __restrict__ w2, const float* __restrict__ w3,
    bf16_t* __restrict__ dst,
    const float* __restrict__ x, bf16_t* __restrict__ xb)
{
  const int tx = threadIdx.x, ty = threadIdx.y;
  if (blockIdx.z == 4) {
    // cvt x: 8192*1024 floats, 1024 blocks * 256 thr * 8 iters * 4 floats
    const int id = (blockIdx.y * 32 + blockIdx.x) * 256 + ty * 32 + tx;
#pragma unroll
    for (int it = 0; it < 8; ++it) {
      const size_t i = ((size_t)id + (size_t)it * 262144) * 4;
      const float4 v = *(const float4*)(x + i);
      bf16x4v o;
      o[0] = (bf16_t)v.x; o[1] = (bf16_t)v.y; o[2] = (bf16_t)v.z; o[3] = (bf16_t)v.w;
      *(bf16x4v*)(xb + i) = o;
    }
    return;
  }
  __shared__ bf16_t tile[32][33];
  const float* src = (blockIdx.z == 0) ? w0 : (blockIdx.z == 1) ? w1
                   : (blockIdx.z == 2) ? w2 : w3;
  bf16_t* d = dst + (size_t)blockIdx.z * 1024 * 1024;
  const int bx = blockIdx.x * 32, by = blockIdx.y * 32;
#pragma unroll
  for (int r = 0; r < 32; r += 8)
    tile[ty + r][tx] = (bf16_t)src[(size_t)(by + ty + r) * 1024 + bx + tx];
  __syncthreads();
#pragma unroll
  for (int r = 0; r < 32; r += 8)
    d[(size_t)(bx + ty + r) * 1024 + by + tx] = tile[tx][ty + r];
}

// ---------------------------------------------------------------------------
// Kernel 2: QKV GEMM, BK=64 (round-8 form, unchanged).
// ---------------------------------------------------------------------------
__global__ __launch_bounds__(256) void gemm_qkv(
    const bf16_t* __restrict__ X, const bf16_t* __restrict__ WtAll,
    const float* __restrict__ bq, const float* __restrict__ bk,
    const float* __restrict__ bv,
    bf16_t* __restrict__ Qb, bf16_t* __restrict__ Kb, bf16_t* __restrict__ Vtb)
{
  __shared__ __align__(16) bf16_t As[128 * 64];
  __shared__ __align__(16) bf16_t Bs[128 * 64];

  const int z = blockIdx.z;
  const bf16_t* Bt = WtAll + (size_t)z * 1024 * 1024;
  const float* bias = (z == 0) ? bq : (z == 1) ? bk : bv;
  const int bm0 = blockIdx.x * 128;
  const int bn0 = blockIdx.y * 128;
  const int t = threadIdx.x;
  const int w = t >> 6, lane = t & 63;
  const int wm = w >> 1, wn = w & 1;
  const int l15 = lane & 15, quad = lane >> 4;
  const int srow8 = lane >> 3;
  const int sp8   = lane & 7;

  f32x4 acc[4][4] = {};

  for (int k0 = 0; k0 < 1024; k0 += 64) {
    __syncthreads();
#pragma unroll
    for (int i = 0; i < 4; ++i) {
      const int row = (w * 4 + i) * 8 + srow8;
      const int c = sp8 ^ (row & 7);
      async16(&As[row * 64 + sp8 * 8], X  + (size_t)(bm0 + row) * 1024 + k0 + c * 8);
      async16(&Bs[row * 64 + sp8 * 8], Bt + (size_t)(bn0 + row) * 1024 + k0 + c * 8);
    }
    __syncthreads();

    bf16x8 af[4][2], bfr[4][2];
#pragma unroll
    for (int mi = 0; mi < 4; ++mi) {
      const int r = wm * 64 + mi * 16 + l15;
#pragma unroll
      for (int kc = 0; kc < 2; ++kc) {
        const int pg = (kc * 4 + quad) ^ (r & 7);
        af[mi][kc] = *(const bf16x8*)&As[r * 64 + pg * 8];
      }
    }
#pragma unroll
    for (int ni = 0; ni < 4; ++ni) {
      const int r = wn * 64 + ni * 16 + l15;
#pragma unroll
      for (int kc = 0; kc < 2; ++kc) {
        const int pg = (kc * 4 + quad) ^ (r & 7);
        bfr[ni][kc] = *(const bf16x8*)&Bs[r * 64 + pg * 8];
      }
    }
#pragma unroll
    for (int kc = 0; kc < 2; ++kc)
#pragma unroll
      for (int mi = 0; mi < 4; ++mi)
#pragma unroll
        for (int ni = 0; ni < 4; ++ni)
          acc[mi][ni] = mfma16(af[mi][kc], bfr[ni][kc], acc[mi][ni]);
  }

  const float QSCALE = 0.045084220f;  // log2(e)/32

#pragma unroll
  for (int ni = 0; ni < 4; ++ni) {
    const int n = bn0 + wn * 64 + ni * 16 + l15;
    const float bb = bias[n];
    const int h = n >> 6, dd = n & 63;
    if (z == 2) {
#pragma unroll
      for (int mi = 0; mi < 4; ++mi) {
        const int m0 = bm0 + wm * 64 + mi * 16 + quad * 4;
        const int bi = m0 >> 11, s = m0 & 2047;
        bf16x4v vk;
#pragma unroll
        for (int r = 0; r < 4; ++r) vk[r] = (bf16_t)(acc[mi][ni][r] + bb);
        *(bf16x4v*)&Vtb[((size_t)(bi * 16 + h) * 64 + dd) * 2048 + s] = vk;
      }
    } else {
#pragma unroll
      for (int mi = 0; mi < 4; ++mi) {
#pragma unroll
        for (int r = 0; r < 4; ++r) {
          const int m = bm0 + wm * 64 + mi * 16 + quad * 4 + r;
          const float v = acc[mi][ni][r] + bb;
          const int bi = m >> 11, s = m & 2047;
          if (z == 0)
            Qb[((size_t)(bi * 16 + h) * 2048 + s) * 64 + dd] = (bf16_t)(v * QSCALE);
          else
            Kb[((size_t)(bi * 16 + h) * 2048 + s) * 64 + dd] = (bf16_t)v;
        }
      }
    }
  }
}

// ---------------------------------------------------------------------------
// Kernel 3: flash attention, S^T formulation, fixed-max exp2 softmax.
// Q-tile 256, wave owns 64 q (ni=0..3).  LDS-staged K/V; wave-private Ps.
// ---------------------------------------------------------------------------
__global__ __launch_bounds__(256) void attn_k(
    const bf16_t* __restrict__ Qb, const bf16_t* __restrict__ Kb,
    const bf16_t* __restrict__ Vtb, const float* __restrict__ mask,
    bf16_t* __restrict__ Ctx)
{
  __shared__ __align__(16) bf16_t Ks[64 * 64];   // [s_k][d], swizzled granules
  __shared__ __align__(16) bf16_t Vs[64 * 64];   // [d][s_k], swizzled granules
  __shared__ __align__(16) bf16_t Ps[256 * 64];  // [q][s_k], swizzled granules
  __shared__ __align__(16) float maskv[64];

  const int qt = blockIdx.x, bh = blockIdx.y;
  const int bi = bh >> 4, h = bh & 15;
  const int q0 = qt * 256;
  const bf16_t* Qh = Qb + (size_t)bh * 2048 * 64;
  const bf16_t* Kh = Kb + (size_t)bh * 2048 * 64;
  const bf16_t* Vh = Vtb + (size_t)bh * 64 * 2048;

  const int t = threadIdx.x;
  const int w = t >> 6, lane = t & 63;
  const int l15 = lane & 15, quad = lane >> 4;

  // Q as B-fragments: q = q0 + w*64 + ni*16 + l15, k = kc*32 + quad*8 + j
  bf16x8 qb[4][2];
#pragma unroll
  for (int ni = 0; ni < 4; ++ni)
#pragma unroll
    for (int kc = 0; kc < 2; ++kc)
      qb[ni][kc] = *(const bf16x8*)&Qh[(size_t)(q0 + w * 64 + ni * 16 + l15) * 64
                                       + kc * 32 + quad * 8];

  bf16x8 ones;
#pragma unroll
  for (int i = 0; i < 8; ++i) ones[i] = (bf16_t)1.0f;

  f32x4 oacc[4][4] = {};      // [d-tile][q-tile]
  f32x4 lacc[4] = {};         // row sums via ones-MFMA

  const int srow = lane >> 3;
  const int sp = lane & 7;

  for (int j = 0; j < 32; ++j) {
    const int k0 = j * 64;
    __syncthreads();
#pragma unroll
    for (int i = 0; i < 2; ++i) {
      const int row = (w * 2 + i) * 8 + srow;
      const int c = sp ^ (row & 7);
      async16(&Ks[row * 64 + sp * 8], Kh + (size_t)(k0 + row) * 64 + c * 8);
      async16(&Vs[row * 64 + sp * 8], Vh + (size_t)row * 2048 + k0 + c * 8);
    }
    if (t < 64) maskv[t] = mask[bi * 2048 + k0 + t] * (-1.442695e9f);
    __syncthreads();

    // S^T = K . Q^T, C initialized to the mask bias; kf loaded per-mi
    f32x4 sacc[4][4];
#pragma unroll
    for (int mi = 0; mi < 4; ++mi) {
      const float4 mk = *(const float4*)&maskv[mi * 16 + quad * 4];
      f32x4 cinit; cinit[0] = mk.x; cinit[1] = mk.y; cinit[2] = mk.z; cinit[3] = mk.w;
#pragma unroll
      for (int ni = 0; ni < 4; ++ni) sacc[mi][ni] = cinit;
    }
#pragma unroll
    for (int mi = 0; mi < 4; ++mi) {
      const int r = mi * 16 + l15;
      const bf16x8 kf0 = *(const bf16x8*)&Ks[r * 64 + ((0 * 4 + quad) ^ (r & 7)) * 8];
      const bf16x8 kf1 = *(const bf16x8*)&Ks[r * 64 + ((1 * 4 + quad) ^ (r & 7)) * 8];
#pragma unroll
      for (int ni = 0; ni < 4; ++ni) {
        sacc[mi][ni] = mfma16(kf0, qb[ni][0], sacc[mi][ni]);
        sacc[mi][ni] = mfma16(kf1, qb[ni][1], sacc[mi][ni]);
      }
    }

    // P = exp2(s'), packed b64 LDS writes (rows wave-private)
#pragma unroll
    for (int ni = 0; ni < 4; ++ni) {
      const int row = w * 64 + ni * 16 + l15;
#pragma unroll
      for (int mi = 0; mi < 4; ++mi) {
        bf16x4v pk;
        pk[0] = (bf16_t)fast_exp2(sacc[mi][ni][0]);
        pk[1] = (bf16_t)fast_exp2(sacc[mi][ni][1]);
        pk[2] = (bf16_t)fast_exp2(sacc[mi][ni][2]);
        pk[3] = (bf16_t)fast_exp2(sacc[mi][ni][3]);
        const int pg = (mi * 2 + (quad >> 1)) ^ (row & 7);
        *(bf16x4v*)&Ps[row * 64 + pg * 8 + (quad & 1) * 4] = pk;
      }
    }

    // O^T += V^T . P ; l += ones . P   (av loaded per-mi; Ps wave-private)
    bf16x8 pb[4][2];
#pragma unroll
    for (int ni = 0; ni < 4; ++ni)
#pragma unroll
      for (int kc = 0; kc < 2; ++kc) {
        const int row = w * 64 + ni * 16 + l15;
        const int pg = (kc * 4 + quad) ^ (row & 7);
        pb[ni][kc] = *(const bf16x8*)&Ps[row * 64 + pg * 8];
      }
#pragma unroll
    for (int mi = 0; mi < 4; ++mi) {
      const int r = mi * 16 + l15;
      const bf16x8 av0 = *(const bf16x8*)&Vs[r * 64 + ((0 * 4 + quad) ^ (r & 7)) * 8];
      const bf16x8 av1 = *(const bf16x8*)&Vs[r * 64 + ((1 * 4 + quad) ^ (r & 7)) * 8];
#pragma unroll
      for (int ni = 0; ni < 4; ++ni) {
        oacc[mi][ni] = mfma16(av0, pb[ni][0], oacc[mi][ni]);
        oacc[mi][ni] = mfma16(av1, pb[ni][1], oacc[mi][ni]);
      }
    }
#pragma unroll
    for (int ni = 0; ni < 4; ++ni) {
      lacc[ni] = mfma16(ones, pb[ni][0], lacc[ni]);
      lacc[ni] = mfma16(ones, pb[ni][1], lacc[ni]);
    }
  }

  // write ctx (B,S,E): lane holds O[q = ni*16+l15][d = mi*16+quad*4+r]
#pragma unroll
  for (int ni = 0; ni < 4; ++ni) {
    const float inv = 1.0f / lacc[ni][0];
    const int s = q0 + w * 64 + ni * 16 + l15;
#pragma unroll
    for (int mi = 0; mi < 4; ++mi) {
      bf16x4v o4;
      o4[0] = (bf16_t)(oacc[mi][ni][0] * inv);
      o4[1] = (bf16_t)(oacc[mi][ni][1] * inv);
      o4[2] = (bf16_t)(oacc[mi][ni][2] * inv);
      o4[3] = (bf16_t)(oacc[mi][ni][3] * inv);
      *(bf16x4v*)&Ctx[((size_t)bi * 2048 + s) * 1024 + h * 64 + mi * 16 + quad * 4] = o4;
    }
  }
}

// ---------------------------------------------------------------------------
// Kernel 4: output projection + bias + residual -> fp32 Add (round-8 form).
// ---------------------------------------------------------------------------
__global__ __launch_bounds__(256) void gemm_proj(
    const bf16_t* __restrict__ Ctx, const bf16_t* __restrict__ WoT,
    const float* __restrict__ bo, const float* __restrict__ Xres,
    float* __restrict__ Add)
{
  __shared__ __align__(16) bf16_t As[128 * 64];
  __shared__ __align__(16) bf16_t Bs[128 * 64];

  const int bm0 = blockIdx.x * 128;
  const int bn0 = blockIdx.y * 128;
  const int t = threadIdx.x;
  const int w = t >> 6, lane = t & 63;
  const int wm = w >> 1, wn = w & 1;
  const int l15 = lane & 15, quad = lane >> 4;
  const int srow8 = lane >> 3;
  const int sp8   = lane & 7;

  f32x4 acc[4][4] = {};

  for (int k0 = 0; k0 < 1024; k0 += 64) {
    __syncthreads();
#pragma unroll
    for (int i = 0; i < 4; ++i) {
      const int row = (w * 4 + i) * 8 + srow8;
      const int c = sp8 ^ (row & 7);
      async16(&As[row * 64 + sp8 * 8], Ctx + (size_t)(bm0 + row) * 1024 + k0 + c * 8);
      async16(&Bs[row * 64 + sp8 * 8], WoT + (size_t)(bn0 + row) * 1024 + k0 + c * 8);
    }
    __syncthreads();

    bf16x8 af[4][2], bfr[4][2];
#pragma unroll
    for (int mi = 0; mi < 4; ++mi) {
      const int r = wm * 64 + mi * 16 + l15;
#pragma unroll
      for (int kc = 0; kc < 2; ++kc) {
        const int pg = (kc * 4 + quad) ^ (r & 7);
        af[mi][kc] = *(const bf16x8*)&As[r * 64 + pg * 8];
      }
    }
#pragma unroll
    for (int ni = 0; ni < 4; ++ni) {
      const int r = wn * 64 + ni * 16 + l15;
#pragma unroll
      for (int kc = 0; kc < 2; ++kc) {
        const int pg = (kc * 4 + quad) ^ (r & 7);
        bfr[ni][kc] = *(const bf16x8*)&Bs[r * 64 + pg * 8];
      }
    }
#pragma unroll
    for (int kc = 0; kc < 2; ++kc)
#pragma unroll
      for (int mi = 0; mi < 4; ++mi)
#pragma unroll
        for (int ni = 0; ni < 4; ++ni)
          acc[mi][ni] = mfma16(af[mi][kc], bfr[ni][kc], acc[mi][ni]);
  }

#pragma unroll
  for (int ni = 0; ni < 4; ++ni) {
    const int n = bn0 + wn * 64 + ni * 16 + l15;
    const float bb = bo[n];
#pragma unroll
    for (int mi = 0; mi < 4; ++mi) {
#pragma unroll
      for (int r = 0; r < 4; ++r) {
        const int m = bm0 + wm * 64 + mi * 16 + quad * 4 + r;
        Add[(size_t)m * 1024 + n] =
            acc[mi][ni][r] + bb + Xres[(size_t)m * 1024 + n];
      }
    }
  }
}

// ---------------------------------------------------------------------------
// Kernel 5: LayerNorm, wave-per-row (4 rows / 256-thr block), no LDS/barriers
// ---------------------------------------------------------------------------
__global__ __launch_bounds__(256) void ln_k(
    const float* __restrict__ A, const float* __restrict__ gamma,
    const float* __restrict__ beta, float* __restrict__ out)
{
  const int wid = threadIdx.x >> 6, lane = threadIdx.x & 63;
  const int row = blockIdx.x * 4 + wid;
  const float* a = A + (size_t)row * 1024;

  float4 v[4];
#pragma unroll
  for (int k = 0; k < 4; ++k) v[k] = ((const float4*)a)[lane + k * 64];

  float s = 0.f;
#pragma unroll
  for (int k = 0; k < 4; ++k) s += (v[k].x + v[k].y) + (v[k].z + v[k].w);
#pragma unroll
  for (int o = 1; o < 64; o <<= 1) s += __shfl_xor(s, o);
  const float mu = s * (1.0f / 1024.0f);

  float q = 0.f;
#pragma unroll
  for (int k = 0; k < 4; ++k) {
    v[k].x -= mu; v[k].y -= mu; v[k].z -= mu; v[k].w -= mu;
    q += (v[k].x * v[k].x + v[k].y * v[k].y) + (v[k].z * v[k].z + v[k].w * v[k].w);
  }
#pragma unroll
  for (int o = 1; o < 64; o <<= 1) q += __shfl_xor(q, o);
  const float rs = rsqrtf(q * (1.0f / 1024.0f) + 1e-6f);

#pragma unroll
  for (int k = 0; k < 4; ++k) {
    const int c = lane + k * 64;
    const float4 g4 = ((const float4*)gamma)[c];
    const float4 b4 = ((const float4*)beta)[c];
    float4 o4;
    o4.x = g4.x * v[k].x * rs + b4.x;
    o4.y = g4.y * v[k].y * rs + b4.y;
    o4.z = g4.z * v[k].z * rs + b4.z;
    o4.w = g4.w * v[k].w * rs + b4.w;
    ((float4*)(out + (size_t)row * 1024))[c] = o4;
  }
}

// ---------------------------------------------------------------------------
extern "C" void kernel_launch(void* const* d_in, const int* in_sizes, int n_in,
                              void* d_out, int out_size, void* d_ws, size_t ws_size,
                              hipStream_t stream)
{
  const float* x     = (const float*)d_in[0];
  const float* mask  = (const float*)d_in[1];
  const float* Wq    = (const float*)d_in[2];
  const float* bq    = (const float*)d_in[3];
  const float* Wk    = (const float*)d_in[4];
  const float* bk    = (const float*)d_in[5];
  const float* Wv    = (const float*)d_in[6];
  const float* bv    = (const float*)d_in[7];
  const float* Wo    = (const float*)d_in[8];
  const float* bo    = (const float*)d_in[9];
  const float* gamma = (const float*)d_in[10];
  const float* beta  = (const float*)d_in[11];
  float* out = (float*)d_out;

  bf16_t* Wt  = (bf16_t*)d_ws;
  bf16_t* Xb  = Wt + (size_t)4 * 1024 * 1024;
  bf16_t* Qb  = Xb + (size_t)8192 * 1024;
  bf16_t* Kb  = Qb + (size_t)8192 * 1024;
  bf16_t* Vtb = Kb + (size_t)8192 * 1024;
  bf16_t* Ctx = Vtb + (size_t)8192 * 1024;
  float*  Add = (float*)(Ctx + (size_t)8192 * 1024);

  prep_k<<<dim3(32, 32, 5), dim3(32, 8), 0, stream>>>(Wq, Wk, Wv, Wo, Wt, x, Xb);
  gemm_qkv<<<dim3(64, 8, 3), 256, 0, stream>>>(Xb, Wt, bq, bk, bv, Qb, Kb, Vtb);
  attn_k<<<dim3(8, 64), 256, 0, stream>>>(Qb, Kb, Vtb, mask, Ctx);
  gemm_proj<<<dim3(64, 8), 256, 0, stream>>>(Ctx, Wt + (size_t)3 * 1024 * 1024, bo, x, Add);
  ln_k<<<2048, 256, 0, stream>>>(Add, gamma, beta, out);
}